// Round 9
// baseline (412.806 us; speedup 1.0000x reference)
//
#include <hip/hip_runtime.h>
#include <stdint.h>

// Problem constants
#define K_CODES 8192
#define D 256
#define NROWS 16384      // 16 * 32 * 32
#define NELEM 4194304    // 16 * 256 * 32 * 32

// ws layout (bytes)
#define WS_ENORM   0x00000u                 // 8192 f32 = 32 KB
#define WS_KEYS    0x08000u                 // 16384 u64 = 128 KB
#define WS_ICOUNTS 0x28000u                 // 8192 i32
#define WS_CURSOR  0x30000u                 // 8192 i32
#define WS_BASE    0x38000u                 // 8192 i32
#define WS_ROWLIST 0x40000u                 // 16384 i32 = 64 KB
#define WS_PART    0x50000u                 // 256 f32
#define WS_APK_HI  0x60000u                 // 16384*256 bf16 frag-packed = 8 MB
#define WS_APK_LO  (WS_APK_HI + 0x800000u)  // 8 MB
#define WS_BPK_HI  (WS_APK_LO + 0x800000u)  // 8192*256 bf16 frag-packed = 4 MB
#define WS_BPK_LO  (WS_BPK_HI + 0x400000u)  // 4 MB

// out offsets (floats), concatenated return order
#define O_QST  0
#define O_LOSS 4194304
#define O_PERP 4194305
#define O_EMB  4194306
#define O_CS   6291458
#define O_EAVG 6299650

typedef unsigned short u16;
typedef __attribute__((ext_vector_type(8))) short bf16x8;
typedef __attribute__((ext_vector_type(16))) float f32x16;

// bf16 round-to-nearest-even split helpers
__device__ __forceinline__ u16 f2bf(float f) {
    uint32_t u = __float_as_uint(f);
    u += 0x7FFFu + ((u >> 16) & 1u);
    return (u16)(u >> 16);
}
__device__ __forceinline__ float bf2f(u16 h) {
    return __uint_as_float(((uint32_t)h) << 16);
}

__device__ __forceinline__ void glds16(const u16* g, u16* lds_base) {
    __builtin_amdgcn_global_load_lds(
        (const __attribute__((address_space(1))) uint32_t*)g,
        (__attribute__((address_space(3))) uint32_t*)lds_base, 16, 0, 0);
}

// Fragment packing (32x32x16 MFMA operand order), for a 32-row group g:
//   Pk[(((g*16 + ks)*64 + lane)*8 + e] = val(row = g*32 + (lane&31),
//                                            k = ks*16 + (lane>>5)*8 + e)
// One wave's frag load = 64 lanes x 16 B CONTIGUOUS 1 KB.

// ---------------------------------------------------------------------------
// Fused prep:
//   blocks [0,512):   x split+transpose+pack -> Apk_hi/Apk_lo
//   blocks [512,768): emb split+pack -> Bpk_hi/Bpk_lo, + enorm
//   blocks [768,832): keys = ~0
//   blocks [832,864): icounts = cursor = 0
__global__ __launch_bounds__(256) void prep_kernel(const float* __restrict__ emb,
                                                   const float* __restrict__ x,
                                                   u16* __restrict__ apk_hi,
                                                   u16* __restrict__ apk_lo,
                                                   u16* __restrict__ bpk_hi,
                                                   u16* __restrict__ bpk_lo,
                                                   float* __restrict__ enorm,
                                                   unsigned long long* __restrict__ keys,
                                                   int* __restrict__ icounts,
                                                   int* __restrict__ cursor) {
    __shared__ u16 Lh[32][264];
    __shared__ u16 Ll[32][264];
    const int bid = blockIdx.x, t = threadIdx.x;
    const int l = t & 63, w = t >> 6;

    if (bid < 512) {
        // ---- x group: rows g*32..g*32+31 (one batch b, contiguous hw) ----
        const int g = bid;
        const int b = g >> 5;
        const int hw0 = (g & 31) << 5;
        // read: half-wave = 32 consecutive hw (128 B), c = w*64 + cc*2 + (l>>5)
        for (int cc = 0; cc < 32; ++cc) {
            const int c = w * 64 + cc * 2 + (l >> 5);
            const float v = x[(((size_t)(b * 256 + c)) << 10) + hw0 + (l & 31)];
            const u16 h = f2bf(v);
            Lh[l & 31][c] = h;
            Ll[l & 31][c] = f2bf(v - bf2f(h));
        }
        __syncthreads();
        // write frag-packed: chunk ch = q*256+t -> ks=ch>>6, lane=ch&63
#pragma unroll
        for (int q = 0; q < 4; ++q) {
            const int ch = q * 256 + t;
            const int ks = ch >> 6, lane = ch & 63;
            const int row = lane & 31;
            const int kb = ks * 16 + ((lane >> 5) << 3);
            const size_t o = ((((size_t)g * 16 + ks) * 64) + lane) * 8;
            *(uint4*)&apk_hi[o] = *(const uint4*)&Lh[row][kb];
            *(uint4*)&apk_lo[o] = *(const uint4*)&Ll[row][kb];
        }
    } else if (bid < 768) {
        // ---- emb group: codes g*32..+31 ----
        const int g = bid - 512;
        const int k0 = g << 5;
        for (int row = 0; row < 32; ++row) {
            const float v = emb[(size_t)(k0 + row) * D + t];   // 1 KB coalesced
            const u16 h = f2bf(v);
            Lh[row][t] = h;
            Ll[row][t] = f2bf(v - bf2f(h));
        }
        __syncthreads();
#pragma unroll
        for (int q = 0; q < 4; ++q) {
            const int ch = q * 256 + t;
            const int ks = ch >> 6, lane = ch & 63;
            const int row = lane & 31;
            const int kb = ks * 16 + ((lane >> 5) << 3);
            const size_t o = ((((size_t)g * 16 + ks) * 64) + lane) * 8;
            *(uint4*)&bpk_hi[o] = *(const uint4*)&Lh[row][kb];
            *(uint4*)&bpk_lo[o] = *(const uint4*)&Ll[row][kb];
        }
        // enorm from reconstructed hi+lo (err ~2^-17, consistent with scores)
        const int row = t >> 3, cq = t & 7;
        float s = 0.f;
        for (int c = cq; c < D; c += 8) {
            const float v = bf2f(Lh[row][c]) + bf2f(Ll[row][c]);
            s = fmaf(v, v, s);
        }
        s += __shfl_xor(s, 1, 64);
        s += __shfl_xor(s, 2, 64);
        s += __shfl_xor(s, 4, 64);
        if (cq == 0) enorm[k0 + row] = s;
    } else if (bid < 832) {
        keys[(bid - 768) * 256 + t] = ~0ull;
    } else {
        const int m = (bid - 832) * 256 + t;
        icounts[m] = 0;
        cursor[m] = 0;
    }
}

// ---------------------------------------------------------------------------
// Distance GEMM, flatmm-style (R9):
//  - 32x32x16 bf16 MFMA (4061 FLOP/cyc/CU vs 3378 for 16x16x32).
//  - Block = 128 threads (2 waves x 32 rows). Grid 1024 = 4 slices x 256
//    row-blocks = 4 blocks/CU (2 waves/SIMD); slice = bx&3 pins one 2 MB
//    Bpk slice per XCD's L2.
//  - A-hi: frag-packed LDS, wave-private, staged once (16 glds16), read as
//    contiguous-1KB ds_read_b128 (conflict-free). A-lo: 64 persistent VGPRs.
//  - B: NEVER in LDS. Frag-packed global (Bpk) -> each load is one fully
//    coalesced 1 KB global_load_dwordx4 into registers, double-buffered one
//    body ahead -> compiler emits partial vmcnt waits. NO K-loop barriers.
//  - Per-ct raw s_barrier keeps the 2-wave pair L1-aligned on the B stream.
#define CT_PER 16      // 16 ct x 128 codes = 2048-code slice
#define NRB 256        // row blocks of 64 rows

__global__ __launch_bounds__(128, 2) void dist_kernel(const u16* __restrict__ apk_hi,
                                                      const u16* __restrict__ apk_lo,
                                                      const u16* __restrict__ bpk_hi,
                                                      const u16* __restrict__ bpk_lo,
                                                      const float* __restrict__ enorm,
                                                      unsigned long long* __restrict__ keys) {
    __shared__ __align__(16) u16 As[16384];   // 2 waves x 16 ks x 512 u16 = 32 KB

    const int t = threadIdx.x, l = t & 63, w = t >> 6;
    const int bx = blockIdx.x;
    const int slice = bx & 3;                 // XCD-pinned (bx%8 -> slice&3)
    const int rb = bx >> 2;                   // 0..255
    const int grb = rb * 2 + w;               // this wave's 32-row group

    // ---- stage A-hi (wave-private, contiguous) ----------------------------
    const u16* asrc = apk_hi + (((size_t)grb * 16) * 64) * 8 + l * 8;
    u16* adst = &As[w * 8192];
#pragma unroll
    for (int ks = 0; ks < 16; ++ks)
        glds16(asrc + ks * 512, adst + ks * 512);

    // ---- A-lo -> 64 persistent VGPRs --------------------------------------
    const u16* lsrc = apk_lo + (((size_t)grb * 16) * 64) * 8 + l * 8;
    bf16x8 falo[16];
#pragma unroll
    for (int ks = 0; ks < 16; ++ks)
        falo[ks] = *(const bf16x8*)(lsrc + ks * 512);

    __syncthreads();                          // drains glds16 (vmcnt) for As

    const u16* bh = bpk_hi + ((size_t)slice * 64 * 16) * 512 + l * 8;
    const u16* bl = bpk_lo + ((size_t)slice * 64 * 16) * 512 + l * 8;

    float rbv[16];
    int rbi[16];
#pragma unroll
    for (int r = 0; r < 16; ++r) { rbv[r] = 1e30f; rbi[r] = 0; }

    f32x16 acc[4];
#pragma unroll
    for (int j = 0; j < 4; ++j) acc[j] = (f32x16)0.f;

    bf16x8 fb[2][8], ahf[2];
    // preload body (ct=0, ks=0)
#pragma unroll
    for (int j = 0; j < 4; ++j) {
        const int off = (j * 16) * 512;
        fb[0][j * 2]     = *(const bf16x8*)(bh + off);
        fb[0][j * 2 + 1] = *(const bf16x8*)(bl + off);
    }
    ahf[0] = *(const bf16x8*)&As[w * 8192 + l * 8];

    for (int ct = 0; ct < CT_PER; ++ct) {
        __builtin_amdgcn_s_barrier();         // pair the 2 waves on B stream
        const int cbase = slice * 2048 + ct * 128;
        float ecr[4];
#pragma unroll
        for (int j = 0; j < 4; ++j) ecr[j] = enorm[cbase + j * 32 + (l & 31)];

#pragma unroll
        for (int ks = 0; ks < 16; ++ks) {
            const int p = ks & 1, nx = p ^ 1;
            // prefetch next body's B + A-hi frags (one body ahead)
            if (ct * 16 + ks < CT_PER * 16 - 1) {
                const int nct = (ks == 15) ? ct + 1 : ct;
                const int nks = (ks + 1) & 15;
#pragma unroll
                for (int j = 0; j < 4; ++j) {
                    const int off = ((nct * 4 + j) * 16 + nks) * 512;
                    fb[nx][j * 2]     = *(const bf16x8*)(bh + off);
                    fb[nx][j * 2 + 1] = *(const bf16x8*)(bl + off);
                }
            }
            ahf[nx] = *(const bf16x8*)&As[w * 8192 + ((ks + 1) & 15) * 512 + l * 8];
            // 12 MFMAs: hh + hl + lh
#pragma unroll
            for (int j = 0; j < 4; ++j) {
                acc[j] = __builtin_amdgcn_mfma_f32_32x32x16_bf16(ahf[p],   fb[p][j * 2],     acc[j], 0, 0, 0);
                acc[j] = __builtin_amdgcn_mfma_f32_32x32x16_bf16(ahf[p],   fb[p][j * 2 + 1], acc[j], 0, 0, 0);
                acc[j] = __builtin_amdgcn_mfma_f32_32x32x16_bf16(falo[ks], fb[p][j * 2],     acc[j], 0, 0, 0);
            }
        }

        // merge ct's 128 codes into running best (j ascending -> lowest idx ties)
#pragma unroll
        for (int j = 0; j < 4; ++j) {
            const int ci = cbase + j * 32 + (l & 31);
#pragma unroll
            for (int r = 0; r < 16; ++r) {
                const float s = fmaf(-2.f, acc[j][r], ecr[j]);
                if (s < rbv[r]) { rbv[r] = s; rbi[r] = ci; }
                acc[j][r] = 0.f;
            }
        }
    }

    // ---- epilogue: reduce over 32 code-lanes, atomicMin u64 keys ----------
    // C/D map (32x32): col = lane&31 (code), row = (r&3) + 8*(r>>2) + 4*(lane>>5)
#pragma unroll
    for (int r = 0; r < 16; ++r) {
        float bv = rbv[r];
        int bi = rbi[r];
#pragma unroll
        for (int m = 1; m < 32; m <<= 1) {
            const float ov = __shfl_xor(bv, m, 64);
            const int oi = __shfl_xor(bi, m, 64);
            if (ov < bv || (ov == bv && oi < bi)) { bv = ov; bi = oi; }
        }
        if ((l & 31) == 0) {
            const int row = (r & 3) + 8 * (r >> 2) + 4 * (l >> 5);
            const int n = rb * 64 + w * 32 + row;
            unsigned int u = __float_as_uint(bv);
            u = (u & 0x80000000u) ? ~u : (u | 0x80000000u);
            const unsigned long long key = ((unsigned long long)u << 32) | (unsigned int)bi;
            atomicMin(&keys[n], key);
        }
    }
}

// ---------------------------------------------------------------------------
// quantized_st + loss partials + integer code counts
__global__ __launch_bounds__(256) void quant_loss_kernel(const float* __restrict__ x,
                                                         const float* __restrict__ emb,
                                                         const unsigned long long* __restrict__ keys,
                                                         float* __restrict__ out,
                                                         float* __restrict__ partials,
                                                         int* __restrict__ icounts) {
    const int blk = blockIdx.x;
    const int b = blk >> 4;
    const int hw0 = (blk & 15) << 6;
    const int l = threadIdx.x & 63;
    const int cq = threadIdx.x >> 6;
    const int hw = hw0 + l;
    const int n = (b << 10) + hw;
    const int code = (int)(keys[n] & 0xFFFFFFFFull);
    if (threadIdx.x < 64) atomicAdd(&icounts[code], 1);
    const float* erow = emb + (size_t)code * D;
    const float* xb = x + (((size_t)b * 256) << 10) + hw;
    float* ob = out + O_QST + (((size_t)b * 256) << 10) + hw;
    float lsum = 0.f;
#pragma unroll 4
    for (int c = cq; c < D; c += 4) {
        const float xv = xb[(size_t)c << 10];
        const float ev = erow[c];
        ob[(size_t)c << 10] = xv + (ev - xv);
        const float d = xv - ev;
        lsum = fmaf(d, d, lsum);
    }
    __shared__ float sm[4];
    const int lane = threadIdx.x & 63, wv = threadIdx.x >> 6;
#pragma unroll
    for (int off = 32; off; off >>= 1) lsum += __shfl_down(lsum, off, 64);
    if (lane == 0) sm[wv] = lsum;
    __syncthreads();
    if (threadIdx.x == 0) partials[blockIdx.x] = sm[0] + sm[1] + sm[2] + sm[3];
}

// ---------------------------------------------------------------------------
// Exclusive scan of icounts -> basearr; also final loss + perplexity scalars.
__global__ __launch_bounds__(256) void scan_final_kernel(const int* __restrict__ icounts,
                                                         int* __restrict__ basearr,
                                                         const float* __restrict__ partials,
                                                         float* __restrict__ out) {
    const int t = threadIdx.x, lane = t & 63, w = t >> 6;
    int loc = 0;
    float ps = 0.f;
    for (int i = 0; i < 32; ++i) {
        const int c = icounts[t * 32 + i];
        loc += c;
        const float p = (float)c * (1.0f / 16384.0f);
        ps += p * logf(p + 1e-10f);
    }
    int v = loc;
#pragma unroll
    for (int off = 1; off < 64; off <<= 1) {
        const int u = __shfl_up(v, off, 64);
        if (lane >= off) v += u;
    }
    __shared__ int wsum[4];
    __shared__ float fs[8];
    if (lane == 63) wsum[w] = v;
    float lp = partials[t];
#pragma unroll
    for (int off = 32; off; off >>= 1) {
        lp += __shfl_down(lp, off, 64);
        ps += __shfl_down(ps, off, 64);
    }
    if (lane == 0) { fs[w] = lp; fs[4 + w] = ps; }
    __syncthreads();
    int pre = 0;
    for (int i = 0; i < w; ++i) pre += wsum[i];
    int b = pre + v - loc;
    for (int i = 0; i < 32; ++i) {
        basearr[t * 32 + i] = b;
        b += icounts[t * 32 + i];
    }
    if (t == 0) {
        out[O_LOSS] = 0.25f * ((fs[0] + fs[1] + fs[2] + fs[3]) / 4194304.0f);
        out[O_PERP] = expf(-(fs[4] + fs[5] + fs[6] + fs[7]));
    }
}

// ---------------------------------------------------------------------------
// Counting-sort slot assignment: rowlist[base[code] + pos] = n
__global__ __launch_bounds__(256) void slot_kernel(const unsigned long long* __restrict__ keys,
                                                   const int* __restrict__ basearr,
                                                   int* __restrict__ cursor,
                                                   int* __restrict__ rowlist) {
    const int n = blockIdx.x * 256 + threadIdx.x;
    const int code = (int)(keys[n] & 0xFFFFFFFFull);
    const int pos = atomicAdd(&cursor[code], 1);
    rowlist[basearr[code] + pos] = n;
}

// ---------------------------------------------------------------------------
// Per-code gather-sum of x rows fused with EMA. x values read from Apk
// (frag-packed) and reconstructed hi+lo.
__global__ __launch_bounds__(256) void gather_ema_kernel(const u16* __restrict__ apk_hi,
                                                         const u16* __restrict__ apk_lo,
                                                         const int* __restrict__ icounts,
                                                         const int* __restrict__ basearr,
                                                         const int* __restrict__ rowlist,
                                                         const float* __restrict__ embed_avg,
                                                         const float* __restrict__ cluster_size,
                                                         float* __restrict__ out) {
    const int k = blockIdx.x, c = threadIdx.x;
    const int cnt = icounts[k], b0 = basearr[k];
    // Apk index for (row n, channel c)
    const int ks = c >> 4, lhalf = (c >> 3) & 1, e = c & 7;
    float s = 0.f;
    for (int t = 0; t < cnt; ++t) {
        const int n = rowlist[b0 + t];  // wave-uniform
        const size_t o = ((((size_t)(n >> 5) * 16 + ks) * 64) + (lhalf << 5) + (n & 31)) * 8 + e;
        s += bf2f(apk_hi[o]) + bf2f(apk_lo[o]);
    }
    const float ncs = cluster_size[k] * 0.99f + 0.01f * (float)cnt;
    const size_t i = (size_t)k * D + c;
    const float na = embed_avg[i] * 0.99f + 0.01f * s;
    out[O_EAVG + i] = na;
    out[O_EMB + i] = na / fmaxf(ncs, 1e-5f);
    if (c == 0) out[O_CS + k] = ncs;
}

// ---------------------------------------------------------------------------
extern "C" void kernel_launch(void* const* d_in, const int* in_sizes, int n_in,
                              void* d_out, int out_size, void* d_ws, size_t ws_size,
                              hipStream_t stream) {
    const float* x            = (const float*)d_in[0];
    const float* emb          = (const float*)d_in[1];
    const float* cluster_size = (const float*)d_in[2];
    const float* embed_avg    = (const float*)d_in[3];
    float* out = (float*)d_out;
    char* ws = (char*)d_ws;

    float* enorm = (float*)(ws + WS_ENORM);
    unsigned long long* keys = (unsigned long long*)(ws + WS_KEYS);
    int* icounts = (int*)(ws + WS_ICOUNTS);
    int* cursor = (int*)(ws + WS_CURSOR);
    int* basearr = (int*)(ws + WS_BASE);
    int* rowlist = (int*)(ws + WS_ROWLIST);
    float* partials = (float*)(ws + WS_PART);
    u16* apk_hi = (u16*)(ws + WS_APK_HI);
    u16* apk_lo = (u16*)(ws + WS_APK_LO);
    u16* bpk_hi = (u16*)(ws + WS_BPK_HI);
    u16* bpk_lo = (u16*)(ws + WS_BPK_LO);

    prep_kernel<<<864, 256, 0, stream>>>(emb, x, apk_hi, apk_lo, bpk_hi, bpk_lo,
                                         enorm, keys, icounts, cursor);
    dist_kernel<<<1024, 128, 0, stream>>>(apk_hi, apk_lo, bpk_hi, bpk_lo, enorm, keys);
    quant_loss_kernel<<<256, 256, 0, stream>>>(x, emb, keys, out, partials, icounts);
    scan_final_kernel<<<1, 256, 0, stream>>>(icounts, basearr, partials, out);
    slot_kernel<<<NROWS / 256, 256, 0, stream>>>(keys, basearr, cursor, rowlist);
    gather_ema_kernel<<<K_CODES, 256, 0, stream>>>(apk_hi, apk_lo, icounts, basearr, rowlist,
                                                   embed_avg, cluster_size, out);
}